// Round 15
// baseline (256.799 us; speedup 1.0000x reference)
//
#include <hip/hip_runtime.h>

#define D_MODEL 512
#define DINNER  1024
#define DSTATE  64
#define DTRANK  32
#define BSZ     2
#define NLEN    2048
#define NROWS   (BSZ*NLEN)   // 4096
#define XDBL_W  (DTRANK + 2*DSTATE)  // 160

typedef __attribute__((ext_vector_type(8))) short  bf16x8;
typedef __attribute__((ext_vector_type(4))) float  f32x4;
typedef __attribute__((ext_vector_type(8))) unsigned short u16x8;

__device__ __forceinline__ unsigned int rne16(float f) {
    unsigned int u = __float_as_uint(f);
    return (u + 0x7fffu + ((u >> 16) & 1)) >> 16;
}
__device__ __forceinline__ float fsilu(float x) {
    return x / (1.f + __builtin_amdgcn_exp2f(-x * 1.44269504f));
}

// ---- device helper: pack fp32 (RxK row-major) -> fragment-major split-bf16 ----
__device__ __forceinline__ void pack_frag(const float* __restrict__ src,
        unsigned short* __restrict__ dst, int R, int RT, int K,
        int gid, int lane) {
    const int kt = gid / RT, rt = gid - kt * RT;
    const int row = (rt << 4) + (lane & 15);
    const int KTK = K >> 5;
    u16x8 hi = {}, lo = {};
    if (row < R) {
        const float* s = src + (size_t)row * K + kt * 32 + ((lane >> 4) << 3);
        float4 f0 = *(const float4*)s;
        float4 f1 = *(const float4*)(s + 4);
        float ff[8] = {f0.x,f0.y,f0.z,f0.w,f1.x,f1.y,f1.z,f1.w};
        #pragma unroll
        for (int j = 0; j < 8; ++j) {
            unsigned int hb = rne16(ff[j]);
            hi[j] = (unsigned short)hb;
            lo[j] = (unsigned short)rne16(ff[j] - __uint_as_float(hb << 16));
        }
    }
    *(u16x8*)(dst + ((size_t)kt * RT + rt) * 512 + lane * 8) = hi;
    *(u16x8*)(dst + ((size_t)(kt + KTK) * RT + rt) * 512 + lane * 8) = lo;
}

// ---- prologue: LN+in_proj-A-pack | 3 weight packs | xdbl zero, by block range ----
__global__ __launch_bounds__(256) void prologue(const float* __restrict__ x,
        const float* __restrict__ nw, const float* __restrict__ nb,
        const float* __restrict__ in_w, const float* __restrict__ x_w,
        const float* __restrict__ out_w, unsigned short* __restrict__ Ap,
        unsigned short* __restrict__ BpIn, unsigned short* __restrict__ BpX,
        unsigned short* __restrict__ BpOut, float* __restrict__ xdbl) {
    __shared__ float xs[16][516];
    const int bid = blockIdx.x;
    const int wid = threadIdx.x >> 6, lane = threadIdx.x & 63;
    if (bid < 256) {
        const int rt = bid;
        const float4* wp = (const float4*)nw;
        const float4* bp = (const float4*)nb;
        const float4 w0 = wp[lane], w1 = wp[lane + 64];
        const float4 b0 = bp[lane], b1 = bp[lane + 64];
        #pragma unroll
        for (int pq = 0; pq < 4; ++pq) {
            const int r = (wid << 2) + pq;
            const int row = (rt << 4) + r;
            const float4* xp = (const float4*)(x + (size_t)row * D_MODEL);
            float4 v0 = xp[lane], v1 = xp[lane + 64];
            float s = v0.x + v0.y + v0.z + v0.w + v1.x + v1.y + v1.z + v1.w;
            float q = v0.x*v0.x + v0.y*v0.y + v0.z*v0.z + v0.w*v0.w
                    + v1.x*v1.x + v1.y*v1.y + v1.z*v1.z + v1.w*v1.w;
            #pragma unroll
            for (int m = 32; m; m >>= 1) { s += __shfl_xor(s, m); q += __shfl_xor(q, m); }
            const float mean = s * (1.f / D_MODEL);
            const float var  = q * (1.f / D_MODEL) - mean * mean;
            const float rstd = rsqrtf(var + 1e-5f);
            float4 o0, o1;
            o0.x = (v0.x - mean) * rstd * w0.x + b0.x;
            o0.y = (v0.y - mean) * rstd * w0.y + b0.y;
            o0.z = (v0.z - mean) * rstd * w0.z + b0.z;
            o0.w = (v0.w - mean) * rstd * w0.w + b0.w;
            o1.x = (v1.x - mean) * rstd * w1.x + b1.x;
            o1.y = (v1.y - mean) * rstd * w1.y + b1.y;
            o1.z = (v1.z - mean) * rstd * w1.z + b1.z;
            o1.w = (v1.w - mean) * rstd * w1.w + b1.w;
            *(float4*)&xs[r][lane << 2] = o0;
            *(float4*)&xs[r][256 + (lane << 2)] = o1;
        }
        __syncthreads();
        const int r = lane & 15;
        const int cq = (lane >> 4) << 3;
        #pragma unroll
        for (int q = 0; q < 4; ++q) {
            const int kt = (wid << 2) + q;       // KTK=16 for K=512
            const int c0 = (kt << 5) + cq;
            float4 f0 = *(const float4*)&xs[r][c0];
            float4 f1 = *(const float4*)&xs[r][c0 + 4];
            float ff[8] = {f0.x,f0.y,f0.z,f0.w,f1.x,f1.y,f1.z,f1.w};
            u16x8 hi, lo;
            #pragma unroll
            for (int j = 0; j < 8; ++j) {
                unsigned int hb = rne16(ff[j]);
                hi[j] = (unsigned short)hb;
                lo[j] = (unsigned short)rne16(ff[j] - __uint_as_float(hb << 16));
            }
            *(u16x8*)(Ap + ((size_t)kt * 256 + rt) * 512 + lane * 8) = hi;
            *(u16x8*)(Ap + ((size_t)(kt + 16) * 256 + rt) * 512 + lane * 8) = lo;
        }
    } else if (bid < 768) {
        pack_frag(in_w, BpIn, 2048, 128, 512, (bid - 256) * 4 + wid, lane);
    } else if (bid < 896) {
        pack_frag(x_w, BpX, 160, 16, 1024, (bid - 768) * 4 + wid, lane);
    } else if (bid < 1152) {
        pack_frag(out_w, BpOut, 512, 32, 1024, (bid - 896) * 4 + wid, lane);
    } else {
        float* p = xdbl + (size_t)(bid - 1152) * 4096 + threadIdx.x * 4;
        const float4 z4 = make_float4(0.f, 0.f, 0.f, 0.f);
        *(float4*)p = z4; *(float4*)(p + 1024) = z4;
        *(float4*)(p + 2048) = z4; *(float4*)(p + 3072) = z4;
    }
}

// ---- MFMA GEMM on packed operands, BK=64 ----
// ATOMIC=false: column blocks with n0<cols3 run `tk` terms (hi*hi, lo*hi,
//               hi*lo via virtual-kt mapping), others 1; direct stores.
// ATOMIC=true : `tk` = K-split factor. blockIdx.z = (kchunk<<1)|term;
//               term 1 (lo*hi) only for n0<cols3; atomicAdd epilogue.
template<int BM, int BN, int WR, int WC, bool ATOMIC>
__global__ __launch_bounds__(256) void gemm_mfma(
        const unsigned short* __restrict__ Ap, const unsigned short* __restrict__ Bp,
        int M, int N, int K, int cols3, int tk,
        float* __restrict__ out0, float* __restrict__ out1, int split) {
    constexpr int MI = BM / (WR * 16);
    constexpr int NI = BN / (WC * 16);
    constexpr int APASS = BM / 64;
    constexpr int BPASS = BN / 64;
    __shared__ __align__(16) unsigned short sA[2 * BM * 32];
    __shared__ __align__(16) unsigned short sB[2 * BN * 32];
    const int tid = threadIdx.x;
    const int wid = tid >> 6, lane = tid & 63;
    const int wr = wid / WC, wc = wid % WC;
    const int m0 = blockIdx.y * BM, n0 = blockIdx.x * BN;
    const int MT = M >> 4, NT = N >> 4;
    const int KTK = K >> 5;
    int KTv, kbase = 0, aoff = 0;
    if (ATOMIC) {
        const int term = blockIdx.z & 1;
        if (term && n0 >= cols3) return;         // uniform block exit
        KTv = KTK / tk;
        kbase = (blockIdx.z >> 1) * KTv;
        aoff = term ? KTK : 0;                   // lo region of A
    } else {
        KTv = (n0 < cols3) ? tk * KTK : KTK;
    }
    f32x4 acc[MI][NI] = {};
    for (int kt2 = 0; kt2 < KTv; kt2 += 2) {
        __syncthreads();
        #pragma unroll
        for (int tt = 0; tt < 2; ++tt) {
            const int kt = kt2 + tt;
            int a_kt, b_kt;
            if (ATOMIC) { a_kt = kbase + kt + aoff; b_kt = kbase + kt; }
            else { a_kt = (kt < 2 * KTK) ? kt : kt - 2 * KTK;   // hi, lo, hi
                   b_kt = (kt < KTK) ? kt : kt - KTK; }         // hi, hi, lo
            const char* gA = (const char*)(Ap + ((size_t)a_kt * MT + (m0 >> 4)) * 512);
            const char* gB = (const char*)(Bp + ((size_t)b_kt * NT + (n0 >> 4)) * 512);
            #pragma unroll
            for (int p = 0; p < APASS; ++p)
                __builtin_amdgcn_global_load_lds(
                    (const __attribute__((address_space(1))) void*)(gA + p * 4096 + tid * 16),
                    (__attribute__((address_space(3))) void*)((char*)sA + tt * BM * 64 + p * 4096 + tid * 16),
                    16, 0, 0);
            #pragma unroll
            for (int p = 0; p < BPASS; ++p)
                __builtin_amdgcn_global_load_lds(
                    (const __attribute__((address_space(1))) void*)(gB + p * 4096 + tid * 16),
                    (__attribute__((address_space(3))) void*)((char*)sB + tt * BN * 64 + p * 4096 + tid * 16),
                    16, 0, 0);
        }
        __syncthreads();
        #pragma unroll
        for (int tt = 0; tt < 2; ++tt) {
            bf16x8 af[MI], bfr[NI];
            #pragma unroll
            for (int mi = 0; mi < MI; ++mi)
                af[mi] = *(const bf16x8*)((const char*)sA + tt*BM*64 + (wr*MI + mi)*1024 + lane*16);
            #pragma unroll
            for (int ni = 0; ni < NI; ++ni)
                bfr[ni] = *(const bf16x8*)((const char*)sB + tt*BN*64 + (wc*NI + ni)*1024 + lane*16);
            #pragma unroll
            for (int mi = 0; mi < MI; ++mi)
                #pragma unroll
                for (int ni = 0; ni < NI; ++ni)
                    acc[mi][ni] = __builtin_amdgcn_mfma_f32_16x16x32_bf16(
                        af[mi], bfr[ni], acc[mi][ni], 0, 0, 0);
        }
    }
    #pragma unroll
    for (int mi = 0; mi < MI; ++mi) {
        #pragma unroll
        for (int ni = 0; ni < NI; ++ni) {
            const int col = n0 + (wc*NI + ni)*16 + (lane & 15);
            const int rb_ = m0 + (wr*MI + mi)*16 + ((lane >> 4) << 2);
            if (col < split) {
                #pragma unroll
                for (int r = 0; r < 4; ++r) {
                    if (ATOMIC) atomicAdd(&out0[(size_t)(rb_ + r) * split + col], acc[mi][ni][r]);
                    else        out0[(size_t)(rb_ + r) * split + col] = acc[mi][ni][r];
                }
            } else if (!ATOMIC && out1 != nullptr) {
                #pragma unroll
                for (int r = 0; r < 4; ++r)
                    out1[(size_t)(rb_ + r) * (N - split) + (col - split)] = acc[mi][ni][r];
            }
        }
    }
}

// ---- fused causal depthwise conv (k=4) + SiLU + x_proj A-pack ----
__global__ __launch_bounds__(256) void conv_pack(const float* __restrict__ xr,
        const float* __restrict__ cw, const float* __restrict__ cb,
        float* __restrict__ xi, unsigned short* __restrict__ Ap) {
    const int wid = threadIdx.x >> 6, lane = threadIdx.x & 63;
    const int gid = (blockIdx.x << 2) + wid;     // [0, 32*256)
    const int kt = gid >> 8, rt = gid & 255;
    const int row = (rt << 4) + (lane & 15);
    const int n = row & (NLEN - 1);
    const int d0 = (kt << 5) + ((lane >> 4) << 3);
    const float* base = xr + (size_t)row * DINNER + d0;
    const float4 z4 = make_float4(0.f, 0.f, 0.f, 0.f);
    float4 c0 = *(const float4*)base,          c1 = *(const float4*)(base + 4);
    float4 a0 = (n >= 1) ? *(const float4*)(base - DINNER)     : z4;
    float4 a1 = (n >= 1) ? *(const float4*)(base - DINNER + 4) : z4;
    float4 b0 = (n >= 2) ? *(const float4*)(base - 2*DINNER)     : z4;
    float4 b1 = (n >= 2) ? *(const float4*)(base - 2*DINNER + 4) : z4;
    float4 e0 = (n >= 3) ? *(const float4*)(base - 3*DINNER)     : z4;
    float4 e1 = (n >= 3) ? *(const float4*)(base - 3*DINNER + 4) : z4;
    float cur[8] = {c0.x,c0.y,c0.z,c0.w,c1.x,c1.y,c1.z,c1.w};
    float p1[8]  = {a0.x,a0.y,a0.z,a0.w,a1.x,a1.y,a1.z,a1.w};
    float p2[8]  = {b0.x,b0.y,b0.z,b0.w,b1.x,b1.y,b1.z,b1.w};
    float p3[8]  = {e0.x,e0.y,e0.z,e0.w,e1.x,e1.y,e1.z,e1.w};
    float o[8];
    u16x8 hi, lo;
    #pragma unroll
    for (int j = 0; j < 8; ++j) {
        const float4 wv = *(const float4*)(cw + (d0 + j) * 4);
        float a = cb[d0 + j];
        a = fmaf(wv.w, cur[j], a);
        a = fmaf(wv.z, p1[j], a);
        a = fmaf(wv.y, p2[j], a);
        a = fmaf(wv.x, p3[j], a);
        o[j] = fsilu(a);
        unsigned int hb = rne16(o[j]);
        hi[j] = (unsigned short)hb;
        lo[j] = (unsigned short)rne16(o[j] - __uint_as_float(hb << 16));
    }
    float* xo = xi + (size_t)row * DINNER + d0;
    *(float4*)xo = make_float4(o[0], o[1], o[2], o[3]);
    *(float4*)(xo + 4) = make_float4(o[4], o[5], o[6], o[7]);
    *(u16x8*)(Ap + ((size_t)kt * 256 + rt) * 512 + lane * 8) = hi;
    *(u16x8*)(Ap + ((size_t)(kt + 32) * 256 + rt) * 512 + lane * 8) = lo;
}

// ---- dt/du tiled GEMV+softplus+transpose ([0,1024)) + quad-bc pack ([1024,1088)) ----
// bc quad layout: bc[(row>>2)*256 + s*4 + (row&3)] = bf16(B) | bf16(C)<<16
__global__ __launch_bounds__(256) void dtdu_kernel(const float* __restrict__ xdbl,
        const float* __restrict__ W, const float* __restrict__ bias,
        const float* __restrict__ u, float* __restrict__ dtT,
        float* __restrict__ duT, unsigned int* __restrict__ bc) {
    if (blockIdx.x >= 1024) {
        const int row0 = (blockIdx.x - 1024) << 6;
        #pragma unroll
        for (int k = 0; k < 16; ++k) {
            const int g = threadIdx.x * 16 + k;      // 0..4095
            const int lr = g >> 6, s = g & 63;
            const int row = row0 + lr;
            const float* src = xdbl + (size_t)row * XDBL_W + DTRANK + s;
            bc[(size_t)(row >> 2) * 256 + s * 4 + (row & 3)] =
                rne16(src[0]) | (rne16(src[DSTATE]) << 16);
        }
        return;
    }
    __shared__ float sdtr[64][33];
    __shared__ float sW[64][33];
    __shared__ float tt[64][65];
    const int nb = blockIdx.x & 63, db = blockIdx.x >> 6;
    const int row0 = nb << 6, d0 = db << 6;
    const int i = threadIdx.x >> 2, kq = (threadIdx.x & 3) << 3;
    {
        const float* s = xdbl + (size_t)(row0 + i) * XDBL_W + kq;
        *(float4*)&sdtr[i][kq]     = *(const float4*)s;
        *(float4*)&sdtr[i][kq + 4] = *(const float4*)(s + 4);
        const float* wsrc = W + (size_t)(d0 + i) * DTRANK + kq;
        *(float4*)&sW[i][kq]     = *(const float4*)wsrc;
        *(float4*)&sW[i][kq + 4] = *(const float4*)(wsrc + 4);
    }
    __syncthreads();
    const int i4 = (threadIdx.x >> 4) << 2;
    const int j4 = (threadIdx.x & 15) << 2;
    float dtv[4][4], duv[4][4];
    {
        float acc[4][4] = {};
        #pragma unroll
        for (int k = 0; k < DTRANK; ++k) {
            float a[4]  = {sdtr[i4][k], sdtr[i4+1][k], sdtr[i4+2][k], sdtr[i4+3][k]};
            float bb[4] = {sW[j4][k], sW[j4+1][k], sW[j4+2][k], sW[j4+3][k]};
            #pragma unroll
            for (int ii = 0; ii < 4; ++ii)
                #pragma unroll
                for (int jj = 0; jj < 4; ++jj)
                    acc[ii][jj] = fmaf(a[ii], bb[jj], acc[ii][jj]);
        }
        float4 bv = *(const float4*)(bias + d0 + j4);
        float bb4[4] = {bv.x, bv.y, bv.z, bv.w};
        #pragma unroll
        for (int ii = 0; ii < 4; ++ii) {
            float4 uv = *(const float4*)(u + (size_t)(row0 + i4 + ii) * DINNER + d0 + j4);
            float uu[4] = {uv.x, uv.y, uv.z, uv.w};
            #pragma unroll
            for (int jj = 0; jj < 4; ++jj) {
                float z = acc[ii][jj] + bb4[jj];
                float dt = (z > 20.f) ? z : log1pf(expf(z));
                dtv[ii][jj] = dt;
                duv[ii][jj] = dt * uu[jj];
            }
        }
    }
    const int b = row0 >> 11;
    const int n0 = row0 & (NLEN - 1);
    const int jt = threadIdx.x >> 2, iq = (threadIdx.x & 3) << 4;
    float* dstD = dtT + ((size_t)(b * DINNER + d0 + jt)) * NLEN + n0 + iq;
    float* dstU = duT + ((size_t)(b * DINNER + d0 + jt)) * NLEN + n0 + iq;
    #pragma unroll
    for (int ii = 0; ii < 4; ++ii)
        #pragma unroll
        for (int jj = 0; jj < 4; ++jj)
            tt[i4 + ii][j4 + jj] = dtv[ii][jj];
    __syncthreads();
    #pragma unroll
    for (int r = 0; r < 4; ++r) {
        float4 o = make_float4(tt[iq+4*r+0][jt], tt[iq+4*r+1][jt],
                               tt[iq+4*r+2][jt], tt[iq+4*r+3][jt]);
        *(float4*)(dstD + 4*r) = o;
    }
    __syncthreads();
    #pragma unroll
    for (int ii = 0; ii < 4; ++ii)
        #pragma unroll
        for (int jj = 0; jj < 4; ++jj)
            tt[i4 + ii][j4 + jj] = duv[ii][jj];
    __syncthreads();
    #pragma unroll
    for (int r = 0; r < 4; ++r) {
        float4 o = make_float4(tt[iq+4*r+0][jt], tt[iq+4*r+1][jt],
                               tt[iq+4*r+2][jt], tt[iq+4*r+3][jt]);
        *(float4*)(dstU + 4*r) = o;
    }
}

// ---------------- selective scan: quad-packed bc; y stored as bf16 ----------------
__global__ __launch_bounds__(256) void scan_kernel(const float* __restrict__ dtT,
        const float* __restrict__ duT, const unsigned int* __restrict__ bc,
        const float* __restrict__ A_log, unsigned short* __restrict__ ytb) {
    __shared__ float p[4][32][65];
    __shared__ float2 dd[4][64];
    const int wid = threadIdx.x >> 6;
    const int w = (blockIdx.x << 2) + wid;   // b*1024+d
    const int lane = threadIdx.x & 63;
    const int b = w >> 10, d = w & (DINNER - 1);
    const float* dtp = dtT + (size_t)w * NLEN;
    const float* dup = duT + (size_t)w * NLEN;
    const unsigned int* bcb = bc + (size_t)b * NLEN * 64 + lane * 4;  // quad layout
    unsigned short* yp = ytb + (size_t)w * NLEN;
    const float kA = -__builtin_amdgcn_exp2f(A_log[d * DSTATE + lane] * 1.44269504f)
                     * 1.44269504f;   // A*log2(e)
    float (*pw)[65] = p[wid];
    float2* ddw = dd[wid];
    const int rn = lane & 31, rs = (lane >> 5) << 5;
    float h = 0.f;
    float gdt = dtp[lane], gdu = dup[lane];
    for (int n0 = 0; n0 < NLEN; n0 += 64) {
        ddw[lane] = make_float2(gdt, gdu);      // wave-private; lgkmcnt-ordered
        if (n0 + 64 < NLEN) { gdt = dtp[n0 + 64 + lane]; gdu = dup[n0 + 64 + lane]; }
        const unsigned int* bq = bcb + (size_t)n0 * 64;   // 16 quads of 256 u32
        #pragma unroll
        for (int half = 0; half < 2; ++half) {
            const unsigned int* bh  = bq + (half << 3) * 256;
            const unsigned int* bh2 = bh + 4 * 256;
            #pragma unroll
            for (int g = 0; g < 8; ++g) {
                const uint4 qv = (g < 4) ? *(const uint4*)(bh + g * 256)
                                         : *(const uint4*)(bh2 + (g - 4) * 256);
                #pragma unroll
                for (int e = 0; e < 4; ++e) {
                    const int j = (g << 2) + e;            // 0..31 within half
                    const unsigned int q = (e == 0) ? qv.x : (e == 1) ? qv.y
                                         : (e == 2) ? qv.z : qv.w;
                    const float2 v = ddw[(half << 5) + j];  // uniform broadcast
                    const float Bv = __uint_as_float(q << 16);
                    const float Cv = __uint_as_float(q & 0xffff0000u);
                    h = fmaf(__builtin_amdgcn_exp2f(kA * v.x), h, v.y * Bv);
                    pw[j][lane] = h * Cv;
                }
            }
            float y0 = 0.f, y1 = 0.f, y2 = 0.f, y3 = 0.f;
            #pragma unroll
            for (int i = 0; i < 32; i += 4) {
                y0 += pw[rn][rs + i];
                y1 += pw[rn][rs + i + 1];
                y2 += pw[rn][rs + i + 2];
                y3 += pw[rn][rs + i + 3];
            }
            float y = (y0 + y1) + (y2 + y3);
            y += __shfl_xor(y, 32);
            if (lane < 32) yp[n0 + (half << 5) + rn] = (unsigned short)rne16(y);
        }
    }
}

// ---- fused gate + out_proj A-pack (reads bf16 yt) ----
__global__ __launch_bounds__(256) void gate_pack(const unsigned short* __restrict__ ytb,
        const float* __restrict__ xi, const float* __restrict__ z,
        const float* __restrict__ Dv, unsigned short* __restrict__ Ap) {
    const int wid = threadIdx.x >> 6, lane = threadIdx.x & 63;
    const int gid = (blockIdx.x << 2) + wid;     // [0, 32*256)
    const int kt = gid >> 8, rt = gid & 255;
    const int row = (rt << 4) + (lane & 15);
    const int n = row & (NLEN - 1), b = row >> 11;
    const int d0 = (kt << 5) + ((lane >> 4) << 3);
    const unsigned short* ytp = ytb + ((size_t)(b * DINNER + d0)) * NLEN + n;
    const float* xp = xi + (size_t)row * DINNER + d0;
    const float* zp = z  + (size_t)row * DINNER + d0;
    float4 x0 = *(const float4*)xp, x1 = *(const float4*)(xp + 4);
    float4 z0 = *(const float4*)zp, z1 = *(const float4*)(zp + 4);
    float4 D0 = *(const float4*)(Dv + d0), D1 = *(const float4*)(Dv + d0 + 4);
    float xv[8] = {x0.x,x0.y,x0.z,x0.w,x1.x,x1.y,x1.z,x1.w};
    float zv[8] = {z0.x,z0.y,z0.z,z0.w,z1.x,z1.y,z1.z,z1.w};
    float dv[8] = {D0.x,D0.y,D0.z,D0.w,D1.x,D1.y,D1.z,D1.w};
    u16x8 hi, lo;
    #pragma unroll
    for (int j = 0; j < 8; ++j) {
        const float yv = __uint_as_float((unsigned int)ytp[(size_t)j * NLEN] << 16);
        const float g = fmaf(xv[j], dv[j], yv) * fsilu(zv[j]);
        unsigned int hb = rne16(g);
        hi[j] = (unsigned short)hb;
        lo[j] = (unsigned short)rne16(g - __uint_as_float(hb << 16));
    }
    *(u16x8*)(Ap + ((size_t)kt * 256 + rt) * 512 + lane * 8) = hi;
    *(u16x8*)(Ap + ((size_t)(kt + 32) * 256 + rt) * 512 + lane * 8) = lo;
}

extern "C" void kernel_launch(void* const* d_in, const int* in_sizes, int n_in,
                              void* d_out, int out_size, void* d_ws, size_t ws_size,
                              hipStream_t stream) {
    const float* x         = (const float*)d_in[0];
    const float* norm_w    = (const float*)d_in[1];
    const float* norm_b    = (const float*)d_in[2];
    const float* in_proj_w = (const float*)d_in[3];
    const float* conv_w    = (const float*)d_in[4];
    const float* conv_b    = (const float*)d_in[5];
    const float* x_proj_w  = (const float*)d_in[6];
    const float* dt_proj_w = (const float*)d_in[7];
    const float* dt_proj_b = (const float*)d_in[8];
    const float* A_log     = (const float*)d_in[9];
    const float* Dvec      = (const float*)d_in[10];
    const float* out_proj_w= (const float*)d_in[11];
    float* out = (float*)d_out;
    float* ws  = (float*)d_ws;

    const size_t M1 = (size_t)1024 * 1024;
    float* dtT    = ws;                 // 4M f
    float* xi_duT = ws + 4*M1;          // xiraw (dead after conv_pack) -> duT
    float* zbuf   = ws + 8*M1;
    float* xibuf  = ws + 12*M1;
    float* xdbl   = ws + 16*M1;         // 0.64M f (atomic-accumulated)
    unsigned short* ytbuf = (unsigned short*)(ws + 17*M1);  // 2M u16 (bf16 y)
    unsigned short* Apack = (unsigned short*)(ws + 21*M1);  // 20MB region
    unsigned int*   bcbuf = (unsigned int*)(ws + 21*M1);    // overlaps Apack (ordered)
    unsigned short* BpIn  = (unsigned short*)(ws + 26*M1);
    unsigned short* BpX   = (unsigned short*)(ws + 27*M1);
    unsigned short* BpOut = (unsigned short*)(ws + 27*M1 + 512*1024);

    // ---- prologue: LN+A-pack | weight packs | xdbl zero ----
    prologue<<<1312, 256, 0, stream>>>(x, norm_w, norm_b, in_proj_w, x_proj_w,
        out_proj_w, Apack, BpIn, BpX, BpOut, xdbl);

    // ---- in_proj: M=4096,N=2048,K=512; xi half 2-term, z half 1-term ----
    gemm_mfma<128,128,2,2,false><<<dim3(16, 32), 256, 0, stream>>>(
        Apack, BpIn, 4096, 2048, 512, /*cols3=*/DINNER, /*tk=*/2,
        xi_duT, zbuf, DINNER);

    // ---- fused conv+SiLU+pack: xibuf fp32 + Apack (x_proj A) ----
    conv_pack<<<(32 * 256) / 4, 256, 0, stream>>>(
        xi_duT, conv_w, conv_b, xibuf, Apack);

    // ---- x_proj: split-K x4, dt cols 2-term; z=(kchunk<<1)|term, atomics ----
    gemm_mfma<128,64,2,2,true><<<dim3(3, 32, 8), 256, 0, stream>>>(
        Apack, BpX, 4096, 256, 1024, /*cols3=*/64, /*tk=ksplit*/4,
        xdbl, nullptr, XDBL_W);

    // ---- dt/du transposes + quad-bc pack (one kernel); then scan ----
    dtdu_kernel<<<1024 + 64, 256, 0, stream>>>(xdbl, dt_proj_w, dt_proj_b,
        xibuf, dtT, xi_duT, bcbuf);
    scan_kernel<<<(BSZ * DINNER) / 4, 256, 0, stream>>>(
        dtT, xi_duT, bcbuf, A_log, ytbuf);

    // ---- fused gate+pack: Apack = out_proj A operand (bc dead) ----
    gate_pack<<<(32 * 256) / 4, 256, 0, stream>>>(
        ytbuf, xibuf, zbuf, Dvec, Apack);

    // ---- out_proj: M=4096,N=512,K=1024; 2-term single dispatch ----
    gemm_mfma<64,64,2,2,false><<<dim3(8, 64), 256, 0, stream>>>(
        Apack, BpOut, 4096, 512, 1024, /*cols3=*/512, /*tk=*/2,
        out, nullptr, D_MODEL);
}

// Round 16
// 236.698 us; speedup vs baseline: 1.0849x; 1.0849x over previous
//
#include <hip/hip_runtime.h>

#define D_MODEL 512
#define DINNER  1024
#define DSTATE  64
#define DTRANK  32
#define BSZ     2
#define NLEN    2048
#define NROWS   (BSZ*NLEN)   // 4096
#define XDBL_W  (DTRANK + 2*DSTATE)  // 160

typedef __attribute__((ext_vector_type(8))) short  bf16x8;
typedef __attribute__((ext_vector_type(4))) float  f32x4;
typedef __attribute__((ext_vector_type(8))) unsigned short u16x8;

__device__ __forceinline__ unsigned int rne16(float f) {
    unsigned int u = __float_as_uint(f);
    return (u + 0x7fffu + ((u >> 16) & 1)) >> 16;
}
__device__ __forceinline__ float fsilu(float x) {
    return x / (1.f + __builtin_amdgcn_exp2f(-x * 1.44269504f));
}

// ---- device helper: pack fp32 (RxK row-major) -> fragment-major split-bf16 ----
__device__ __forceinline__ void pack_frag(const float* __restrict__ src,
        unsigned short* __restrict__ dst, int R, int RT, int K,
        int gid, int lane) {
    const int kt = gid / RT, rt = gid - kt * RT;
    const int row = (rt << 4) + (lane & 15);
    const int KTK = K >> 5;
    u16x8 hi = {}, lo = {};
    if (row < R) {
        const float* s = src + (size_t)row * K + kt * 32 + ((lane >> 4) << 3);
        float4 f0 = *(const float4*)s;
        float4 f1 = *(const float4*)(s + 4);
        float ff[8] = {f0.x,f0.y,f0.z,f0.w,f1.x,f1.y,f1.z,f1.w};
        #pragma unroll
        for (int j = 0; j < 8; ++j) {
            unsigned int hb = rne16(ff[j]);
            hi[j] = (unsigned short)hb;
            lo[j] = (unsigned short)rne16(ff[j] - __uint_as_float(hb << 16));
        }
    }
    *(u16x8*)(dst + ((size_t)kt * RT + rt) * 512 + lane * 8) = hi;
    *(u16x8*)(dst + ((size_t)(kt + KTK) * RT + rt) * 512 + lane * 8) = lo;
}

// ---- prologue: LN+in_proj-A-pack | BpIn pack | xdbl zero ----
__global__ __launch_bounds__(256) void prologue(const float* __restrict__ x,
        const float* __restrict__ nw, const float* __restrict__ nb,
        const float* __restrict__ in_w, unsigned short* __restrict__ Ap,
        unsigned short* __restrict__ BpIn, float* __restrict__ xdbl) {
    __shared__ float xs[16][516];
    const int bid = blockIdx.x;
    const int wid = threadIdx.x >> 6, lane = threadIdx.x & 63;
    if (bid < 256) {
        const int rt = bid;
        const float4* wp = (const float4*)nw;
        const float4* bp = (const float4*)nb;
        const float4 w0 = wp[lane], w1 = wp[lane + 64];
        const float4 b0 = bp[lane], b1 = bp[lane + 64];
        #pragma unroll
        for (int pq = 0; pq < 4; ++pq) {
            const int r = (wid << 2) + pq;
            const int row = (rt << 4) + r;
            const float4* xp = (const float4*)(x + (size_t)row * D_MODEL);
            float4 v0 = xp[lane], v1 = xp[lane + 64];
            float s = v0.x + v0.y + v0.z + v0.w + v1.x + v1.y + v1.z + v1.w;
            float q = v0.x*v0.x + v0.y*v0.y + v0.z*v0.z + v0.w*v0.w
                    + v1.x*v1.x + v1.y*v1.y + v1.z*v1.z + v1.w*v1.w;
            #pragma unroll
            for (int m = 32; m; m >>= 1) { s += __shfl_xor(s, m); q += __shfl_xor(q, m); }
            const float mean = s * (1.f / D_MODEL);
            const float var  = q * (1.f / D_MODEL) - mean * mean;
            const float rstd = rsqrtf(var + 1e-5f);
            float4 o0, o1;
            o0.x = (v0.x - mean) * rstd * w0.x + b0.x;
            o0.y = (v0.y - mean) * rstd * w0.y + b0.y;
            o0.z = (v0.z - mean) * rstd * w0.z + b0.z;
            o0.w = (v0.w - mean) * rstd * w0.w + b0.w;
            o1.x = (v1.x - mean) * rstd * w1.x + b1.x;
            o1.y = (v1.y - mean) * rstd * w1.y + b1.y;
            o1.z = (v1.z - mean) * rstd * w1.z + b1.z;
            o1.w = (v1.w - mean) * rstd * w1.w + b1.w;
            *(float4*)&xs[r][lane << 2] = o0;
            *(float4*)&xs[r][256 + (lane << 2)] = o1;
        }
        __syncthreads();
        const int r = lane & 15;
        const int cq = (lane >> 4) << 3;
        #pragma unroll
        for (int q = 0; q < 4; ++q) {
            const int kt = (wid << 2) + q;       // KTK=16 for K=512
            const int c0 = (kt << 5) + cq;
            float4 f0 = *(const float4*)&xs[r][c0];
            float4 f1 = *(const float4*)&xs[r][c0 + 4];
            float ff[8] = {f0.x,f0.y,f0.z,f0.w,f1.x,f1.y,f1.z,f1.w};
            u16x8 hi, lo;
            #pragma unroll
            for (int j = 0; j < 8; ++j) {
                unsigned int hb = rne16(ff[j]);
                hi[j] = (unsigned short)hb;
                lo[j] = (unsigned short)rne16(ff[j] - __uint_as_float(hb << 16));
            }
            *(u16x8*)(Ap + ((size_t)kt * 256 + rt) * 512 + lane * 8) = hi;
            *(u16x8*)(Ap + ((size_t)(kt + 16) * 256 + rt) * 512 + lane * 8) = lo;
        }
    } else if (bid < 768) {
        pack_frag(in_w, BpIn, 2048, 128, 512, (bid - 256) * 4 + wid, lane);
    } else {
        float* p = xdbl + (size_t)(bid - 768) * 4096 + threadIdx.x * 4;
        const float4 z4 = make_float4(0.f, 0.f, 0.f, 0.f);
        *(float4*)p = z4; *(float4*)(p + 1024) = z4;
        *(float4*)(p + 2048) = z4; *(float4*)(p + 3072) = z4;
    }
}

// ---- MFMA GEMM on packed operands, BK=64 ----
// ATOMIC=false: column blocks with n0<cols3 run `tk` terms (hi*hi, lo*hi,
//               hi*lo via virtual-kt mapping), others 1; direct stores.
// ATOMIC=true : `tk` = K-split factor. blockIdx.z = (kchunk<<1)|term;
//               term 1 (lo*hi) only for n0<cols3; atomicAdd epilogue.
template<int BM, int BN, int WR, int WC, bool ATOMIC>
__global__ __launch_bounds__(256) void gemm_mfma(
        const unsigned short* __restrict__ Ap, const unsigned short* __restrict__ Bp,
        int M, int N, int K, int cols3, int tk,
        float* __restrict__ out0, float* __restrict__ out1, int split) {
    constexpr int MI = BM / (WR * 16);
    constexpr int NI = BN / (WC * 16);
    constexpr int APASS = BM / 64;
    constexpr int BPASS = BN / 64;
    __shared__ __align__(16) unsigned short sA[2 * BM * 32];
    __shared__ __align__(16) unsigned short sB[2 * BN * 32];
    const int tid = threadIdx.x;
    const int wid = tid >> 6, lane = tid & 63;
    const int wr = wid / WC, wc = wid % WC;
    const int m0 = blockIdx.y * BM, n0 = blockIdx.x * BN;
    const int MT = M >> 4, NT = N >> 4;
    const int KTK = K >> 5;
    int KTv, kbase = 0, aoff = 0;
    if (ATOMIC) {
        const int term = blockIdx.z & 1;
        if (term && n0 >= cols3) return;         // uniform block exit
        KTv = KTK / tk;
        kbase = (blockIdx.z >> 1) * KTv;
        aoff = term ? KTK : 0;                   // lo region of A
    } else {
        KTv = (n0 < cols3) ? tk * KTK : KTK;
    }
    f32x4 acc[MI][NI] = {};
    for (int kt2 = 0; kt2 < KTv; kt2 += 2) {
        __syncthreads();
        #pragma unroll
        for (int tt = 0; tt < 2; ++tt) {
            const int kt = kt2 + tt;
            int a_kt, b_kt;
            if (ATOMIC) { a_kt = kbase + kt + aoff; b_kt = kbase + kt; }
            else { a_kt = (kt < 2 * KTK) ? kt : kt - 2 * KTK;   // hi, lo, hi
                   b_kt = (kt < KTK) ? kt : kt - KTK; }         // hi, hi, lo
            const char* gA = (const char*)(Ap + ((size_t)a_kt * MT + (m0 >> 4)) * 512);
            const char* gB = (const char*)(Bp + ((size_t)b_kt * NT + (n0 >> 4)) * 512);
            #pragma unroll
            for (int p = 0; p < APASS; ++p)
                __builtin_amdgcn_global_load_lds(
                    (const __attribute__((address_space(1))) void*)(gA + p * 4096 + tid * 16),
                    (__attribute__((address_space(3))) void*)((char*)sA + tt * BM * 64 + p * 4096 + tid * 16),
                    16, 0, 0);
            #pragma unroll
            for (int p = 0; p < BPASS; ++p)
                __builtin_amdgcn_global_load_lds(
                    (const __attribute__((address_space(1))) void*)(gB + p * 4096 + tid * 16),
                    (__attribute__((address_space(3))) void*)((char*)sB + tt * BN * 64 + p * 4096 + tid * 16),
                    16, 0, 0);
        }
        __syncthreads();
        #pragma unroll
        for (int tt = 0; tt < 2; ++tt) {
            bf16x8 af[MI], bfr[NI];
            #pragma unroll
            for (int mi = 0; mi < MI; ++mi)
                af[mi] = *(const bf16x8*)((const char*)sA + tt*BM*64 + (wr*MI + mi)*1024 + lane*16);
            #pragma unroll
            for (int ni = 0; ni < NI; ++ni)
                bfr[ni] = *(const bf16x8*)((const char*)sB + tt*BN*64 + (wc*NI + ni)*1024 + lane*16);
            #pragma unroll
            for (int mi = 0; mi < MI; ++mi)
                #pragma unroll
                for (int ni = 0; ni < NI; ++ni)
                    acc[mi][ni] = __builtin_amdgcn_mfma_f32_16x16x32_bf16(
                        af[mi], bfr[ni], acc[mi][ni], 0, 0, 0);
        }
    }
    #pragma unroll
    for (int mi = 0; mi < MI; ++mi) {
        #pragma unroll
        for (int ni = 0; ni < NI; ++ni) {
            const int col = n0 + (wc*NI + ni)*16 + (lane & 15);
            const int rb_ = m0 + (wr*MI + mi)*16 + ((lane >> 4) << 2);
            if (col < split) {
                #pragma unroll
                for (int r = 0; r < 4; ++r) {
                    if (ATOMIC) atomicAdd(&out0[(size_t)(rb_ + r) * split + col], acc[mi][ni][r]);
                    else        out0[(size_t)(rb_ + r) * split + col] = acc[mi][ni][r];
                }
            } else if (!ATOMIC && out1 != nullptr) {
                #pragma unroll
                for (int r = 0; r < 4; ++r)
                    out1[(size_t)(rb_ + r) * (N - split) + (col - split)] = acc[mi][ni][r];
            }
        }
    }
}

// ---- fused causal conv (k=4) + SiLU + x_proj A-pack; tail blocks pack BpX ----
__global__ __launch_bounds__(256) void conv_pack(const float* __restrict__ xr,
        const float* __restrict__ cw, const float* __restrict__ cb,
        float* __restrict__ xi, unsigned short* __restrict__ Ap,
        const float* __restrict__ x_w, unsigned short* __restrict__ BpX) {
    const int wid = threadIdx.x >> 6, lane = threadIdx.x & 63;
    if (blockIdx.x >= 2048) {   // BpX pack: 128 blocks, gid in [0,512)
        pack_frag(x_w, BpX, 160, 16, 1024, (blockIdx.x - 2048) * 4 + wid, lane);
        return;
    }
    const int gid = (blockIdx.x << 2) + wid;     // [0, 32*256)
    const int kt = gid >> 8, rt = gid & 255;
    const int row = (rt << 4) + (lane & 15);
    const int n = row & (NLEN - 1);
    const int d0 = (kt << 5) + ((lane >> 4) << 3);
    const float* base = xr + (size_t)row * DINNER + d0;
    const float4 z4 = make_float4(0.f, 0.f, 0.f, 0.f);
    float4 c0 = *(const float4*)base,          c1 = *(const float4*)(base + 4);
    float4 a0 = (n >= 1) ? *(const float4*)(base - DINNER)     : z4;
    float4 a1 = (n >= 1) ? *(const float4*)(base - DINNER + 4) : z4;
    float4 b0 = (n >= 2) ? *(const float4*)(base - 2*DINNER)     : z4;
    float4 b1 = (n >= 2) ? *(const float4*)(base - 2*DINNER + 4) : z4;
    float4 e0 = (n >= 3) ? *(const float4*)(base - 3*DINNER)     : z4;
    float4 e1 = (n >= 3) ? *(const float4*)(base - 3*DINNER + 4) : z4;
    float cur[8] = {c0.x,c0.y,c0.z,c0.w,c1.x,c1.y,c1.z,c1.w};
    float p1[8]  = {a0.x,a0.y,a0.z,a0.w,a1.x,a1.y,a1.z,a1.w};
    float p2[8]  = {b0.x,b0.y,b0.z,b0.w,b1.x,b1.y,b1.z,b1.w};
    float p3[8]  = {e0.x,e0.y,e0.z,e0.w,e1.x,e1.y,e1.z,e1.w};
    float o[8];
    u16x8 hi, lo;
    #pragma unroll
    for (int j = 0; j < 8; ++j) {
        const float4 wv = *(const float4*)(cw + (d0 + j) * 4);
        float a = cb[d0 + j];
        a = fmaf(wv.w, cur[j], a);
        a = fmaf(wv.z, p1[j], a);
        a = fmaf(wv.y, p2[j], a);
        a = fmaf(wv.x, p3[j], a);
        o[j] = fsilu(a);
        unsigned int hb = rne16(o[j]);
        hi[j] = (unsigned short)hb;
        lo[j] = (unsigned short)rne16(o[j] - __uint_as_float(hb << 16));
    }
    float* xo = xi + (size_t)row * DINNER + d0;
    *(float4*)xo = make_float4(o[0], o[1], o[2], o[3]);
    *(float4*)(xo + 4) = make_float4(o[4], o[5], o[6], o[7]);
    *(u16x8*)(Ap + ((size_t)kt * 256 + rt) * 512 + lane * 8) = hi;
    *(u16x8*)(Ap + ((size_t)(kt + 32) * 256 + rt) * 512 + lane * 8) = lo;
}

// ---- dt/du tiled GEMV+softplus+transpose ([0,1024)) + quad-bc pack ([1024,1088)) ----
// bc quad layout: bc[(row>>2)*256 + s*4 + (row&3)] = bf16(B) | bf16(C)<<16
__global__ __launch_bounds__(256) void dtdu_kernel(const float* __restrict__ xdbl,
        const float* __restrict__ W, const float* __restrict__ bias,
        const float* __restrict__ u, float* __restrict__ dtT,
        float* __restrict__ duT, unsigned int* __restrict__ bc) {
    if (blockIdx.x >= 1024) {
        const int row0 = (blockIdx.x - 1024) << 6;
        #pragma unroll
        for (int k = 0; k < 16; ++k) {
            const int g = threadIdx.x * 16 + k;      // 0..4095
            const int lr = g >> 6, s = g & 63;
            const int row = row0 + lr;
            const float* src = xdbl + (size_t)row * XDBL_W + DTRANK + s;
            bc[(size_t)(row >> 2) * 256 + s * 4 + (row & 3)] =
                rne16(src[0]) | (rne16(src[DSTATE]) << 16);
        }
        return;
    }
    __shared__ float sdtr[64][33];
    __shared__ float sW[64][33];
    __shared__ float tt[64][65];
    const int nb = blockIdx.x & 63, db = blockIdx.x >> 6;
    const int row0 = nb << 6, d0 = db << 6;
    const int i = threadIdx.x >> 2, kq = (threadIdx.x & 3) << 3;
    {
        const float* s = xdbl + (size_t)(row0 + i) * XDBL_W + kq;
        *(float4*)&sdtr[i][kq]     = *(const float4*)s;
        *(float4*)&sdtr[i][kq + 4] = *(const float4*)(s + 4);
        const float* wsrc = W + (size_t)(d0 + i) * DTRANK + kq;
        *(float4*)&sW[i][kq]     = *(const float4*)wsrc;
        *(float4*)&sW[i][kq + 4] = *(const float4*)(wsrc + 4);
    }
    __syncthreads();
    const int i4 = (threadIdx.x >> 4) << 2;
    const int j4 = (threadIdx.x & 15) << 2;
    float dtv[4][4], duv[4][4];
    {
        float acc[4][4] = {};
        #pragma unroll
        for (int k = 0; k < DTRANK; ++k) {
            float a[4]  = {sdtr[i4][k], sdtr[i4+1][k], sdtr[i4+2][k], sdtr[i4+3][k]};
            float bb[4] = {sW[j4][k], sW[j4+1][k], sW[j4+2][k], sW[j4+3][k]};
            #pragma unroll
            for (int ii = 0; ii < 4; ++ii)
                #pragma unroll
                for (int jj = 0; jj < 4; ++jj)
                    acc[ii][jj] = fmaf(a[ii], bb[jj], acc[ii][jj]);
        }
        float4 bv = *(const float4*)(bias + d0 + j4);
        float bb4[4] = {bv.x, bv.y, bv.z, bv.w};
        #pragma unroll
        for (int ii = 0; ii < 4; ++ii) {
            float4 uv = *(const float4*)(u + (size_t)(row0 + i4 + ii) * DINNER + d0 + j4);
            float uu[4] = {uv.x, uv.y, uv.z, uv.w};
            #pragma unroll
            for (int jj = 0; jj < 4; ++jj) {
                float z = acc[ii][jj] + bb4[jj];
                float dt = (z > 20.f) ? z : log1pf(expf(z));
                dtv[ii][jj] = dt;
                duv[ii][jj] = dt * uu[jj];
            }
        }
    }
    const int b = row0 >> 11;
    const int n0 = row0 & (NLEN - 1);
    const int jt = threadIdx.x >> 2, iq = (threadIdx.x & 3) << 4;
    float* dstD = dtT + ((size_t)(b * DINNER + d0 + jt)) * NLEN + n0 + iq;
    float* dstU = duT + ((size_t)(b * DINNER + d0 + jt)) * NLEN + n0 + iq;
    #pragma unroll
    for (int ii = 0; ii < 4; ++ii)
        #pragma unroll
        for (int jj = 0; jj < 4; ++jj)
            tt[i4 + ii][j4 + jj] = dtv[ii][jj];
    __syncthreads();
    #pragma unroll
    for (int r = 0; r < 4; ++r) {
        float4 o = make_float4(tt[iq+4*r+0][jt], tt[iq+4*r+1][jt],
                               tt[iq+4*r+2][jt], tt[iq+4*r+3][jt]);
        *(float4*)(dstD + 4*r) = o;
    }
    __syncthreads();
    #pragma unroll
    for (int ii = 0; ii < 4; ++ii)
        #pragma unroll
        for (int jj = 0; jj < 4; ++jj)
            tt[i4 + ii][j4 + jj] = duv[ii][jj];
    __syncthreads();
    #pragma unroll
    for (int r = 0; r < 4; ++r) {
        float4 o = make_float4(tt[iq+4*r+0][jt], tt[iq+4*r+1][jt],
                               tt[iq+4*r+2][jt], tt[iq+4*r+3][jt]);
        *(float4*)(dstU + 4*r) = o;
    }
}

// ---------------- selective scan: quad-packed bc; y stored as bf16 ----------------
__global__ __launch_bounds__(256) void scan_kernel(const float* __restrict__ dtT,
        const float* __restrict__ duT, const unsigned int* __restrict__ bc,
        const float* __restrict__ A_log, unsigned short* __restrict__ ytb) {
    __shared__ float p[4][32][65];
    __shared__ float2 dd[4][64];
    const int wid = threadIdx.x >> 6;
    const int w = (blockIdx.x << 2) + wid;   // b*1024+d
    const int lane = threadIdx.x & 63;
    const int b = w >> 10, d = w & (DINNER - 1);
    const float* dtp = dtT + (size_t)w * NLEN;
    const float* dup = duT + (size_t)w * NLEN;
    const unsigned int* bcb = bc + (size_t)b * NLEN * 64 + lane * 4;  // quad layout
    unsigned short* yp = ytb + (size_t)w * NLEN;
    const float kA = -__builtin_amdgcn_exp2f(A_log[d * DSTATE + lane] * 1.44269504f)
                     * 1.44269504f;   // A*log2(e)
    float (*pw)[65] = p[wid];
    float2* ddw = dd[wid];
    const int rn = lane & 31, rs = (lane >> 5) << 5;
    float h = 0.f;
    float gdt = dtp[lane], gdu = dup[lane];
    for (int n0 = 0; n0 < NLEN; n0 += 64) {
        ddw[lane] = make_float2(gdt, gdu);      // wave-private; lgkmcnt-ordered
        if (n0 + 64 < NLEN) { gdt = dtp[n0 + 64 + lane]; gdu = dup[n0 + 64 + lane]; }
        const unsigned int* bq = bcb + (size_t)n0 * 64;   // 16 quads of 256 u32
        #pragma unroll
        for (int half = 0; half < 2; ++half) {
            const unsigned int* bh  = bq + (half << 3) * 256;
            const unsigned int* bh2 = bh + 4 * 256;
            #pragma unroll
            for (int g = 0; g < 8; ++g) {
                const uint4 qv = (g < 4) ? *(const uint4*)(bh + g * 256)
                                         : *(const uint4*)(bh2 + (g - 4) * 256);
                #pragma unroll
                for (int e = 0; e < 4; ++e) {
                    const int j = (g << 2) + e;            // 0..31 within half
                    const unsigned int q = (e == 0) ? qv.x : (e == 1) ? qv.y
                                         : (e == 2) ? qv.z : qv.w;
                    const float2 v = ddw[(half << 5) + j];  // uniform broadcast
                    const float Bv = __uint_as_float(q << 16);
                    const float Cv = __uint_as_float(q & 0xffff0000u);
                    h = fmaf(__builtin_amdgcn_exp2f(kA * v.x), h, v.y * Bv);
                    pw[j][lane] = h * Cv;
                }
            }
            float y0 = 0.f, y1 = 0.f, y2 = 0.f, y3 = 0.f;
            #pragma unroll
            for (int i = 0; i < 32; i += 4) {
                y0 += pw[rn][rs + i];
                y1 += pw[rn][rs + i + 1];
                y2 += pw[rn][rs + i + 2];
                y3 += pw[rn][rs + i + 3];
            }
            float y = (y0 + y1) + (y2 + y3);
            y += __shfl_xor(y, 32);
            if (lane < 32) yp[n0 + (half << 5) + rn] = (unsigned short)rne16(y);
        }
    }
}

// ---- fused gate + out_proj A-pack; tail blocks pack BpOut ----
__global__ __launch_bounds__(256) void gate_pack(const unsigned short* __restrict__ ytb,
        const float* __restrict__ xi, const float* __restrict__ z,
        const float* __restrict__ Dv, unsigned short* __restrict__ Ap,
        const float* __restrict__ out_w, unsigned short* __restrict__ BpOut) {
    const int wid = threadIdx.x >> 6, lane = threadIdx.x & 63;
    if (blockIdx.x >= 2048) {   // BpOut pack: 256 blocks, gid in [0,1024)
        pack_frag(out_w, BpOut, 512, 32, 1024, (blockIdx.x - 2048) * 4 + wid, lane);
        return;
    }
    const int gid = (blockIdx.x << 2) + wid;     // [0, 32*256)
    const int kt = gid >> 8, rt = gid & 255;
    const int row = (rt << 4) + (lane & 15);
    const int n = row & (NLEN - 1), b = row >> 11;
    const int d0 = (kt << 5) + ((lane >> 4) << 3);
    const unsigned short* ytp = ytb + ((size_t)(b * DINNER + d0)) * NLEN + n;
    const float* xp = xi + (size_t)row * DINNER + d0;
    const float* zp = z  + (size_t)row * DINNER + d0;
    float4 x0 = *(const float4*)xp, x1 = *(const float4*)(xp + 4);
    float4 z0 = *(const float4*)zp, z1 = *(const float4*)(zp + 4);
    float4 D0 = *(const float4*)(Dv + d0), D1 = *(const float4*)(Dv + d0 + 4);
    float xv[8] = {x0.x,x0.y,x0.z,x0.w,x1.x,x1.y,x1.z,x1.w};
    float zv[8] = {z0.x,z0.y,z0.z,z0.w,z1.x,z1.y,z1.z,z1.w};
    float dv[8] = {D0.x,D0.y,D0.z,D0.w,D1.x,D1.y,D1.z,D1.w};
    u16x8 hi, lo;
    #pragma unroll
    for (int j = 0; j < 8; ++j) {
        const float yv = __uint_as_float((unsigned int)ytp[(size_t)j * NLEN] << 16);
        const float g = fmaf(xv[j], dv[j], yv) * fsilu(zv[j]);
        unsigned int hb = rne16(g);
        hi[j] = (unsigned short)hb;
        lo[j] = (unsigned short)rne16(g - __uint_as_float(hb << 16));
    }
    *(u16x8*)(Ap + ((size_t)kt * 256 + rt) * 512 + lane * 8) = hi;
    *(u16x8*)(Ap + ((size_t)(kt + 32) * 256 + rt) * 512 + lane * 8) = lo;
}

extern "C" void kernel_launch(void* const* d_in, const int* in_sizes, int n_in,
                              void* d_out, int out_size, void* d_ws, size_t ws_size,
                              hipStream_t stream) {
    const float* x         = (const float*)d_in[0];
    const float* norm_w    = (const float*)d_in[1];
    const float* norm_b    = (const float*)d_in[2];
    const float* in_proj_w = (const float*)d_in[3];
    const float* conv_w    = (const float*)d_in[4];
    const float* conv_b    = (const float*)d_in[5];
    const float* x_proj_w  = (const float*)d_in[6];
    const float* dt_proj_w = (const float*)d_in[7];
    const float* dt_proj_b = (const float*)d_in[8];
    const float* A_log     = (const float*)d_in[9];
    const float* Dvec      = (const float*)d_in[10];
    const float* out_proj_w= (const float*)d_in[11];
    float* out = (float*)d_out;
    float* ws  = (float*)d_ws;

    const size_t M1 = (size_t)1024 * 1024;
    float* dtT    = ws;                 // 4M f
    float* xi_duT = ws + 4*M1;          // xiraw (dead after conv_pack) -> duT
    float* zbuf   = ws + 8*M1;
    float* xibuf  = ws + 12*M1;
    float* xdbl   = ws + 16*M1;         // 0.64M f (atomic-accumulated)
    unsigned short* ytbuf = (unsigned short*)(ws + 17*M1);  // 2M u16 (bf16 y)
    unsigned short* Apack = (unsigned short*)(ws + 21*M1);  // 20MB region
    unsigned int*   bcbuf = (unsigned int*)(ws + 21*M1);    // overlaps Apack (ordered)
    unsigned short* BpIn  = (unsigned short*)(ws + 26*M1);
    unsigned short* BpX   = (unsigned short*)(ws + 27*M1);
    unsigned short* BpOut = (unsigned short*)(ws + 27*M1 + 512*1024);

    // ---- prologue: LN+A-pack | BpIn pack | xdbl zero (928 blocks) ----
    prologue<<<928, 256, 0, stream>>>(x, norm_w, norm_b, in_proj_w,
        Apack, BpIn, xdbl);

    // ---- in_proj: M=4096,N=2048,K=512; all 1-term bf16 ----
    gemm_mfma<128,128,2,2,false><<<dim3(16, 32), 256, 0, stream>>>(
        Apack, BpIn, 4096, 2048, 512, /*cols3=*/DINNER, /*tk=*/1,
        xi_duT, zbuf, DINNER);

    // ---- fused conv+SiLU+pack (+BpX pack in tail blocks) ----
    conv_pack<<<2048 + 128, 256, 0, stream>>>(
        xi_duT, conv_w, conv_b, xibuf, Apack, x_proj_w, BpX);

    // ---- x_proj: split-K x4, dt cols 2-term; z=(kchunk<<1)|term, atomics ----
    gemm_mfma<128,64,2,2,true><<<dim3(3, 32, 8), 256, 0, stream>>>(
        Apack, BpX, 4096, 256, 1024, /*cols3=*/64, /*tk=ksplit*/4,
        xdbl, nullptr, XDBL_W);

    // ---- dt/du transposes + quad-bc pack (one kernel); then scan ----
    dtdu_kernel<<<1024 + 64, 256, 0, stream>>>(xdbl, dt_proj_w, dt_proj_b,
        xibuf, dtT, xi_duT, bcbuf);
    scan_kernel<<<(BSZ * DINNER) / 4, 256, 0, stream>>>(
        dtT, xi_duT, bcbuf, A_log, ytbuf);

    // ---- fused gate+pack (+BpOut pack in tail blocks) ----
    gate_pack<<<2048 + 256, 256, 0, stream>>>(
        ytbuf, xibuf, zbuf, Dvec, Apack, out_proj_w, BpOut);

    // ---- out_proj: M=4096,N=512,K=1024; 1-term bf16 ----
    gemm_mfma<64,64,2,2,false><<<dim3(8, 64), 256, 0, stream>>>(
        Apack, BpOut, 4096, 512, 1024, /*cols3=*/512, /*tk=*/1,
        out, nullptr, D_MODEL);
}

// Round 17
// 235.754 us; speedup vs baseline: 1.0893x; 1.0040x over previous
//
#include <hip/hip_runtime.h>

#define D_MODEL 512
#define DINNER  1024
#define DSTATE  64
#define DTRANK  32
#define BSZ     2
#define NLEN    2048
#define NROWS   (BSZ*NLEN)   // 4096
#define XDBL_W  (DTRANK + 2*DSTATE)  // 160

typedef __attribute__((ext_vector_type(8))) short  bf16x8;
typedef __attribute__((ext_vector_type(4))) float  f32x4;
typedef __attribute__((ext_vector_type(8))) unsigned short u16x8;

__device__ __forceinline__ unsigned int rne16(float f) {
    unsigned int u = __float_as_uint(f);
    return (u + 0x7fffu + ((u >> 16) & 1)) >> 16;
}
__device__ __forceinline__ float fsilu(float x) {
    return x / (1.f + __builtin_amdgcn_exp2f(-x * 1.44269504f));
}

// ---- device helper: pack fp32 (RxK row-major) -> fragment-major split-bf16 ----
__device__ __forceinline__ void pack_frag(const float* __restrict__ src,
        unsigned short* __restrict__ dst, int R, int RT, int K,
        int gid, int lane) {
    const int kt = gid / RT, rt = gid - kt * RT;
    const int row = (rt << 4) + (lane & 15);
    const int KTK = K >> 5;
    u16x8 hi = {}, lo = {};
    if (row < R) {
        const float* s = src + (size_t)row * K + kt * 32 + ((lane >> 4) << 3);
        float4 f0 = *(const float4*)s;
        float4 f1 = *(const float4*)(s + 4);
        float ff[8] = {f0.x,f0.y,f0.z,f0.w,f1.x,f1.y,f1.z,f1.w};
        #pragma unroll
        for (int j = 0; j < 8; ++j) {
            unsigned int hb = rne16(ff[j]);
            hi[j] = (unsigned short)hb;
            lo[j] = (unsigned short)rne16(ff[j] - __uint_as_float(hb << 16));
        }
    }
    *(u16x8*)(dst + ((size_t)kt * RT + rt) * 512 + lane * 8) = hi;
    *(u16x8*)(dst + ((size_t)(kt + KTK) * RT + rt) * 512 + lane * 8) = lo;
}

// ---- prologue: LN+in_proj-A-pack | BpIn pack | xdbl zero ----
__global__ __launch_bounds__(256) void prologue(const float* __restrict__ x,
        const float* __restrict__ nw, const float* __restrict__ nb,
        const float* __restrict__ in_w, unsigned short* __restrict__ Ap,
        unsigned short* __restrict__ BpIn, float* __restrict__ xdbl) {
    __shared__ float xs[16][516];
    const int bid = blockIdx.x;
    const int wid = threadIdx.x >> 6, lane = threadIdx.x & 63;
    if (bid < 256) {
        const int rt = bid;
        const float4* wp = (const float4*)nw;
        const float4* bp = (const float4*)nb;
        const float4 w0 = wp[lane], w1 = wp[lane + 64];
        const float4 b0 = bp[lane], b1 = bp[lane + 64];
        #pragma unroll
        for (int pq = 0; pq < 4; ++pq) {
            const int r = (wid << 2) + pq;
            const int row = (rt << 4) + r;
            const float4* xp = (const float4*)(x + (size_t)row * D_MODEL);
            float4 v0 = xp[lane], v1 = xp[lane + 64];
            float s = v0.x + v0.y + v0.z + v0.w + v1.x + v1.y + v1.z + v1.w;
            float q = v0.x*v0.x + v0.y*v0.y + v0.z*v0.z + v0.w*v0.w
                    + v1.x*v1.x + v1.y*v1.y + v1.z*v1.z + v1.w*v1.w;
            #pragma unroll
            for (int m = 32; m; m >>= 1) { s += __shfl_xor(s, m); q += __shfl_xor(q, m); }
            const float mean = s * (1.f / D_MODEL);
            const float var  = q * (1.f / D_MODEL) - mean * mean;
            const float rstd = rsqrtf(var + 1e-5f);
            float4 o0, o1;
            o0.x = (v0.x - mean) * rstd * w0.x + b0.x;
            o0.y = (v0.y - mean) * rstd * w0.y + b0.y;
            o0.z = (v0.z - mean) * rstd * w0.z + b0.z;
            o0.w = (v0.w - mean) * rstd * w0.w + b0.w;
            o1.x = (v1.x - mean) * rstd * w1.x + b1.x;
            o1.y = (v1.y - mean) * rstd * w1.y + b1.y;
            o1.z = (v1.z - mean) * rstd * w1.z + b1.z;
            o1.w = (v1.w - mean) * rstd * w1.w + b1.w;
            *(float4*)&xs[r][lane << 2] = o0;
            *(float4*)&xs[r][256 + (lane << 2)] = o1;
        }
        __syncthreads();
        const int r = lane & 15;
        const int cq = (lane >> 4) << 3;
        #pragma unroll
        for (int q = 0; q < 4; ++q) {
            const int kt = (wid << 2) + q;       // KTK=16 for K=512
            const int c0 = (kt << 5) + cq;
            float4 f0 = *(const float4*)&xs[r][c0];
            float4 f1 = *(const float4*)&xs[r][c0 + 4];
            float ff[8] = {f0.x,f0.y,f0.z,f0.w,f1.x,f1.y,f1.z,f1.w};
            u16x8 hi, lo;
            #pragma unroll
            for (int j = 0; j < 8; ++j) {
                unsigned int hb = rne16(ff[j]);
                hi[j] = (unsigned short)hb;
                lo[j] = (unsigned short)rne16(ff[j] - __uint_as_float(hb << 16));
            }
            *(u16x8*)(Ap + ((size_t)kt * 256 + rt) * 512 + lane * 8) = hi;
            *(u16x8*)(Ap + ((size_t)(kt + 16) * 256 + rt) * 512 + lane * 8) = lo;
        }
    } else if (bid < 768) {
        pack_frag(in_w, BpIn, 2048, 128, 512, (bid - 256) * 4 + wid, lane);
    } else {
        float* p = xdbl + (size_t)(bid - 768) * 4096 + threadIdx.x * 4;
        const float4 z4 = make_float4(0.f, 0.f, 0.f, 0.f);
        *(float4*)p = z4; *(float4*)(p + 1024) = z4;
        *(float4*)(p + 2048) = z4; *(float4*)(p + 3072) = z4;
    }
}

// ---- MFMA GEMM on packed operands, BK=64 ----
// ATOMIC=false: column blocks with n0<cols3 run `tk` terms (hi*hi, lo*hi,
//               hi*lo via virtual-kt mapping), others 1; direct stores.
// ATOMIC=true : `tk` = K-split factor. blockIdx.z = (kchunk<<1)|term;
//               term 1 (lo*hi) only for n0<cols3; atomicAdd epilogue.
template<int BM, int BN, int WR, int WC, bool ATOMIC>
__global__ __launch_bounds__(256) void gemm_mfma(
        const unsigned short* __restrict__ Ap, const unsigned short* __restrict__ Bp,
        int M, int N, int K, int cols3, int tk,
        float* __restrict__ out0, float* __restrict__ out1, int split) {
    constexpr int MI = BM / (WR * 16);
    constexpr int NI = BN / (WC * 16);
    constexpr int APASS = BM / 64;
    constexpr int BPASS = BN / 64;
    __shared__ __align__(16) unsigned short sA[2 * BM * 32];
    __shared__ __align__(16) unsigned short sB[2 * BN * 32];
    const int tid = threadIdx.x;
    const int wid = tid >> 6, lane = tid & 63;
    const int wr = wid / WC, wc = wid % WC;
    const int m0 = blockIdx.y * BM, n0 = blockIdx.x * BN;
    const int MT = M >> 4, NT = N >> 4;
    const int KTK = K >> 5;
    int KTv, kbase = 0, aoff = 0;
    if (ATOMIC) {
        const int term = blockIdx.z & 1;
        if (term && n0 >= cols3) return;         // uniform block exit
        KTv = KTK / tk;
        kbase = (blockIdx.z >> 1) * KTv;
        aoff = term ? KTK : 0;                   // lo region of A
    } else {
        KTv = (n0 < cols3) ? tk * KTK : KTK;
    }
    f32x4 acc[MI][NI] = {};
    for (int kt2 = 0; kt2 < KTv; kt2 += 2) {
        __syncthreads();
        #pragma unroll
        for (int tt = 0; tt < 2; ++tt) {
            const int kt = kt2 + tt;
            int a_kt, b_kt;
            if (ATOMIC) { a_kt = kbase + kt + aoff; b_kt = kbase + kt; }
            else { a_kt = (kt < 2 * KTK) ? kt : kt - 2 * KTK;   // hi, lo, hi
                   b_kt = (kt < KTK) ? kt : kt - KTK; }         // hi, hi, lo
            const char* gA = (const char*)(Ap + ((size_t)a_kt * MT + (m0 >> 4)) * 512);
            const char* gB = (const char*)(Bp + ((size_t)b_kt * NT + (n0 >> 4)) * 512);
            #pragma unroll
            for (int p = 0; p < APASS; ++p)
                __builtin_amdgcn_global_load_lds(
                    (const __attribute__((address_space(1))) void*)(gA + p * 4096 + tid * 16),
                    (__attribute__((address_space(3))) void*)((char*)sA + tt * BM * 64 + p * 4096 + tid * 16),
                    16, 0, 0);
            #pragma unroll
            for (int p = 0; p < BPASS; ++p)
                __builtin_amdgcn_global_load_lds(
                    (const __attribute__((address_space(1))) void*)(gB + p * 4096 + tid * 16),
                    (__attribute__((address_space(3))) void*)((char*)sB + tt * BN * 64 + p * 4096 + tid * 16),
                    16, 0, 0);
        }
        __syncthreads();
        #pragma unroll
        for (int tt = 0; tt < 2; ++tt) {
            bf16x8 af[MI], bfr[NI];
            #pragma unroll
            for (int mi = 0; mi < MI; ++mi)
                af[mi] = *(const bf16x8*)((const char*)sA + tt*BM*64 + (wr*MI + mi)*1024 + lane*16);
            #pragma unroll
            for (int ni = 0; ni < NI; ++ni)
                bfr[ni] = *(const bf16x8*)((const char*)sB + tt*BN*64 + (wc*NI + ni)*1024 + lane*16);
            #pragma unroll
            for (int mi = 0; mi < MI; ++mi)
                #pragma unroll
                for (int ni = 0; ni < NI; ++ni)
                    acc[mi][ni] = __builtin_amdgcn_mfma_f32_16x16x32_bf16(
                        af[mi], bfr[ni], acc[mi][ni], 0, 0, 0);
        }
    }
    #pragma unroll
    for (int mi = 0; mi < MI; ++mi) {
        #pragma unroll
        for (int ni = 0; ni < NI; ++ni) {
            const int col = n0 + (wc*NI + ni)*16 + (lane & 15);
            const int rb_ = m0 + (wr*MI + mi)*16 + ((lane >> 4) << 2);
            if (col < split) {
                #pragma unroll
                for (int r = 0; r < 4; ++r) {
                    if (ATOMIC) atomicAdd(&out0[(size_t)(rb_ + r) * split + col], acc[mi][ni][r]);
                    else        out0[(size_t)(rb_ + r) * split + col] = acc[mi][ni][r];
                }
            } else if (!ATOMIC && out1 != nullptr) {
                #pragma unroll
                for (int r = 0; r < 4; ++r)
                    out1[(size_t)(rb_ + r) * (N - split) + (col - split)] = acc[mi][ni][r];
            }
        }
    }
}

// ---- fused causal conv (k=4) + SiLU + x_proj A-pack; tail blocks pack BpX ----
__global__ __launch_bounds__(256) void conv_pack(const float* __restrict__ xr,
        const float* __restrict__ cw, const float* __restrict__ cb,
        float* __restrict__ xi, unsigned short* __restrict__ Ap,
        const float* __restrict__ x_w, unsigned short* __restrict__ BpX) {
    const int wid = threadIdx.x >> 6, lane = threadIdx.x & 63;
    if (blockIdx.x >= 2048) {   // BpX pack: 128 blocks, gid in [0,512)
        pack_frag(x_w, BpX, 160, 16, 1024, (blockIdx.x - 2048) * 4 + wid, lane);
        return;
    }
    const int gid = (blockIdx.x << 2) + wid;     // [0, 32*256)
    const int kt = gid >> 8, rt = gid & 255;
    const int row = (rt << 4) + (lane & 15);
    const int n = row & (NLEN - 1);
    const int d0 = (kt << 5) + ((lane >> 4) << 3);
    const float* base = xr + (size_t)row * DINNER + d0;
    const float4 z4 = make_float4(0.f, 0.f, 0.f, 0.f);
    float4 c0 = *(const float4*)base,          c1 = *(const float4*)(base + 4);
    float4 a0 = (n >= 1) ? *(const float4*)(base - DINNER)     : z4;
    float4 a1 = (n >= 1) ? *(const float4*)(base - DINNER + 4) : z4;
    float4 b0 = (n >= 2) ? *(const float4*)(base - 2*DINNER)     : z4;
    float4 b1 = (n >= 2) ? *(const float4*)(base - 2*DINNER + 4) : z4;
    float4 e0 = (n >= 3) ? *(const float4*)(base - 3*DINNER)     : z4;
    float4 e1 = (n >= 3) ? *(const float4*)(base - 3*DINNER + 4) : z4;
    float cur[8] = {c0.x,c0.y,c0.z,c0.w,c1.x,c1.y,c1.z,c1.w};
    float p1[8]  = {a0.x,a0.y,a0.z,a0.w,a1.x,a1.y,a1.z,a1.w};
    float p2[8]  = {b0.x,b0.y,b0.z,b0.w,b1.x,b1.y,b1.z,b1.w};
    float p3[8]  = {e0.x,e0.y,e0.z,e0.w,e1.x,e1.y,e1.z,e1.w};
    float o[8];
    u16x8 hi, lo;
    #pragma unroll
    for (int j = 0; j < 8; ++j) {
        const float4 wv = *(const float4*)(cw + (d0 + j) * 4);
        float a = cb[d0 + j];
        a = fmaf(wv.w, cur[j], a);
        a = fmaf(wv.z, p1[j], a);
        a = fmaf(wv.y, p2[j], a);
        a = fmaf(wv.x, p3[j], a);
        o[j] = fsilu(a);
        unsigned int hb = rne16(o[j]);
        hi[j] = (unsigned short)hb;
        lo[j] = (unsigned short)rne16(o[j] - __uint_as_float(hb << 16));
    }
    float* xo = xi + (size_t)row * DINNER + d0;
    *(float4*)xo = make_float4(o[0], o[1], o[2], o[3]);
    *(float4*)(xo + 4) = make_float4(o[4], o[5], o[6], o[7]);
    *(u16x8*)(Ap + ((size_t)kt * 256 + rt) * 512 + lane * 8) = hi;
    *(u16x8*)(Ap + ((size_t)(kt + 32) * 256 + rt) * 512 + lane * 8) = lo;
}

// ---- dt/du tiled GEMV+softplus+transpose ([0,1024)) + quad-bc pack ([1024,1088)) ----
// bc quad layout: bc[(row>>2)*256 + s*4 + (row&3)] = bf16(B) | bf16(C)<<16
__global__ __launch_bounds__(256) void dtdu_kernel(const float* __restrict__ xdbl,
        const float* __restrict__ W, const float* __restrict__ bias,
        const float* __restrict__ u, float* __restrict__ dtT,
        float* __restrict__ duT, unsigned int* __restrict__ bc) {
    if (blockIdx.x >= 1024) {
        const int row0 = (blockIdx.x - 1024) << 6;
        #pragma unroll
        for (int k = 0; k < 16; ++k) {
            const int g = threadIdx.x * 16 + k;      // 0..4095
            const int lr = g >> 6, s = g & 63;
            const int row = row0 + lr;
            const float* src = xdbl + (size_t)row * XDBL_W + DTRANK + s;
            bc[(size_t)(row >> 2) * 256 + s * 4 + (row & 3)] =
                rne16(src[0]) | (rne16(src[DSTATE]) << 16);
        }
        return;
    }
    __shared__ float sdtr[64][33];
    __shared__ float sW[64][33];
    __shared__ float tt[64][65];
    const int nb = blockIdx.x & 63, db = blockIdx.x >> 6;
    const int row0 = nb << 6, d0 = db << 6;
    const int i = threadIdx.x >> 2, kq = (threadIdx.x & 3) << 3;
    {
        const float* s = xdbl + (size_t)(row0 + i) * XDBL_W + kq;
        *(float4*)&sdtr[i][kq]     = *(const float4*)s;
        *(float4*)&sdtr[i][kq + 4] = *(const float4*)(s + 4);
        const float* wsrc = W + (size_t)(d0 + i) * DTRANK + kq;
        *(float4*)&sW[i][kq]     = *(const float4*)wsrc;
        *(float4*)&sW[i][kq + 4] = *(const float4*)(wsrc + 4);
    }
    __syncthreads();
    const int i4 = (threadIdx.x >> 4) << 2;
    const int j4 = (threadIdx.x & 15) << 2;
    float dtv[4][4], duv[4][4];
    {
        float acc[4][4] = {};
        #pragma unroll
        for (int k = 0; k < DTRANK; ++k) {
            float a[4]  = {sdtr[i4][k], sdtr[i4+1][k], sdtr[i4+2][k], sdtr[i4+3][k]};
            float bb[4] = {sW[j4][k], sW[j4+1][k], sW[j4+2][k], sW[j4+3][k]};
            #pragma unroll
            for (int ii = 0; ii < 4; ++ii)
                #pragma unroll
                for (int jj = 0; jj < 4; ++jj)
                    acc[ii][jj] = fmaf(a[ii], bb[jj], acc[ii][jj]);
        }
        float4 bv = *(const float4*)(bias + d0 + j4);
        float bb4[4] = {bv.x, bv.y, bv.z, bv.w};
        #pragma unroll
        for (int ii = 0; ii < 4; ++ii) {
            float4 uv = *(const float4*)(u + (size_t)(row0 + i4 + ii) * DINNER + d0 + j4);
            float uu[4] = {uv.x, uv.y, uv.z, uv.w};
            #pragma unroll
            for (int jj = 0; jj < 4; ++jj) {
                float z = acc[ii][jj] + bb4[jj];
                float dt = (z > 20.f) ? z : log1pf(expf(z));
                dtv[ii][jj] = dt;
                duv[ii][jj] = dt * uu[jj];
            }
        }
    }
    const int b = row0 >> 11;
    const int n0 = row0 & (NLEN - 1);
    const int jt = threadIdx.x >> 2, iq = (threadIdx.x & 3) << 4;
    float* dstD = dtT + ((size_t)(b * DINNER + d0 + jt)) * NLEN + n0 + iq;
    float* dstU = duT + ((size_t)(b * DINNER + d0 + jt)) * NLEN + n0 + iq;
    #pragma unroll
    for (int ii = 0; ii < 4; ++ii)
        #pragma unroll
        for (int jj = 0; jj < 4; ++jj)
            tt[i4 + ii][j4 + jj] = dtv[ii][jj];
    __syncthreads();
    #pragma unroll
    for (int r = 0; r < 4; ++r) {
        float4 o = make_float4(tt[iq+4*r+0][jt], tt[iq+4*r+1][jt],
                               tt[iq+4*r+2][jt], tt[iq+4*r+3][jt]);
        *(float4*)(dstD + 4*r) = o;
    }
    __syncthreads();
    #pragma unroll
    for (int ii = 0; ii < 4; ++ii)
        #pragma unroll
        for (int jj = 0; jj < 4; ++jj)
            tt[i4 + ii][j4 + jj] = duv[ii][jj];
    __syncthreads();
    #pragma unroll
    for (int r = 0; r < 4; ++r) {
        float4 o = make_float4(tt[iq+4*r+0][jt], tt[iq+4*r+1][jt],
                               tt[iq+4*r+2][jt], tt[iq+4*r+3][jt]);
        *(float4*)(dstU + 4*r) = o;
    }
}

// ---------------- selective scan: quad-packed bc; y stored as bf16 ----------------
// pad 66: phase-A writes 2-way (free); phase-B reads as float2 (b64, 8B-aligned)
__global__ __launch_bounds__(256) void scan_kernel(const float* __restrict__ dtT,
        const float* __restrict__ duT, const unsigned int* __restrict__ bc,
        const float* __restrict__ A_log, unsigned short* __restrict__ ytb) {
    __shared__ float p[4][32][66];
    __shared__ float2 dd[4][64];
    const int wid = threadIdx.x >> 6;
    const int w = (blockIdx.x << 2) + wid;   // b*1024+d
    const int lane = threadIdx.x & 63;
    const int b = w >> 10, d = w & (DINNER - 1);
    const float* dtp = dtT + (size_t)w * NLEN;
    const float* dup = duT + (size_t)w * NLEN;
    const unsigned int* bcb = bc + (size_t)b * NLEN * 64 + lane * 4;  // quad layout
    unsigned short* yp = ytb + (size_t)w * NLEN;
    const float kA = -__builtin_amdgcn_exp2f(A_log[d * DSTATE + lane] * 1.44269504f)
                     * 1.44269504f;   // A*log2(e)
    float (*pw)[66] = p[wid];
    float2* ddw = dd[wid];
    const int rn = lane & 31, rs = (lane >> 5) << 5;
    float h = 0.f;
    float gdt = dtp[lane], gdu = dup[lane];
    for (int n0 = 0; n0 < NLEN; n0 += 64) {
        ddw[lane] = make_float2(gdt, gdu);      // wave-private; lgkmcnt-ordered
        if (n0 + 64 < NLEN) { gdt = dtp[n0 + 64 + lane]; gdu = dup[n0 + 64 + lane]; }
        const unsigned int* bq = bcb + (size_t)n0 * 64;   // 16 quads of 256 u32
        #pragma unroll
        for (int half = 0; half < 2; ++half) {
            const unsigned int* bh  = bq + (half << 3) * 256;
            const unsigned int* bh2 = bh + 4 * 256;
            #pragma unroll
            for (int g = 0; g < 8; ++g) {
                const uint4 qv = (g < 4) ? *(const uint4*)(bh + g * 256)
                                         : *(const uint4*)(bh2 + (g - 4) * 256);
                #pragma unroll
                for (int e = 0; e < 4; ++e) {
                    const int j = (g << 2) + e;            // 0..31 within half
                    const unsigned int q = (e == 0) ? qv.x : (e == 1) ? qv.y
                                         : (e == 2) ? qv.z : qv.w;
                    const float2 v = ddw[(half << 5) + j];  // uniform broadcast
                    const float Bv = __uint_as_float(q << 16);
                    const float Cv = __uint_as_float(q & 0xffff0000u);
                    h = fmaf(__builtin_amdgcn_exp2f(kA * v.x), h, v.y * Bv);
                    pw[j][lane] = h * Cv;
                }
            }
            float y0 = 0.f, y1 = 0.f, y2 = 0.f, y3 = 0.f;
            const float2* prow = (const float2*)&pw[rn][rs];  // 8B aligned (66 even)
            #pragma unroll
            for (int i = 0; i < 16; i += 2) {
                float2 a2 = prow[i], b2 = prow[i + 1];
                y0 += a2.x; y1 += a2.y; y2 += b2.x; y3 += b2.y;
            }
            float y = (y0 + y1) + (y2 + y3);
            y += __shfl_xor(y, 32);
            if (lane < 32) yp[n0 + (half << 5) + rn] = (unsigned short)rne16(y);
        }
    }
}

// ---- fused gate + out_proj A-pack; tail blocks pack BpOut ----
__global__ __launch_bounds__(256) void gate_pack(const unsigned short* __restrict__ ytb,
        const float* __restrict__ xi, const float* __restrict__ z,
        const float* __restrict__ Dv, unsigned short* __restrict__ Ap,
        const float* __restrict__ out_w, unsigned short* __restrict__ BpOut) {
    const int wid = threadIdx.x >> 6, lane = threadIdx.x & 63;
    if (blockIdx.x >= 2048) {   // BpOut pack: 256 blocks, gid in [0,1024)
        pack_frag(out_w, BpOut, 512, 32, 1024, (blockIdx.x - 2048) * 4 + wid, lane);
        return;
    }
    const int gid = (blockIdx.x << 2) + wid;     // [0, 32*256)
    const int kt = gid >> 8, rt = gid & 255;
    const int row = (rt << 4) + (lane & 15);
    const int n = row & (NLEN - 1), b = row >> 11;
    const int d0 = (kt << 5) + ((lane >> 4) << 3);
    const unsigned short* ytp = ytb + ((size_t)(b * DINNER + d0)) * NLEN + n;
    const float* xp = xi + (size_t)row * DINNER + d0;
    const float* zp = z  + (size_t)row * DINNER + d0;
    float4 x0 = *(const float4*)xp, x1 = *(const float4*)(xp + 4);
    float4 z0 = *(const float4*)zp, z1 = *(const float4*)(zp + 4);
    float4 D0 = *(const float4*)(Dv + d0), D1 = *(const float4*)(Dv + d0 + 4);
    float xv[8] = {x0.x,x0.y,x0.z,x0.w,x1.x,x1.y,x1.z,x1.w};
    float zv[8] = {z0.x,z0.y,z0.z,z0.w,z1.x,z1.y,z1.z,z1.w};
    float dv[8] = {D0.x,D0.y,D0.z,D0.w,D1.x,D1.y,D1.z,D1.w};
    u16x8 hi, lo;
    #pragma unroll
    for (int j = 0; j < 8; ++j) {
        const float yv = __uint_as_float((unsigned int)ytp[(size_t)j * NLEN] << 16);
        const float g = fmaf(xv[j], dv[j], yv) * fsilu(zv[j]);
        unsigned int hb = rne16(g);
        hi[j] = (unsigned short)hb;
        lo[j] = (unsigned short)rne16(g - __uint_as_float(hb << 16));
    }
    *(u16x8*)(Ap + ((size_t)kt * 256 + rt) * 512 + lane * 8) = hi;
    *(u16x8*)(Ap + ((size_t)(kt + 32) * 256 + rt) * 512 + lane * 8) = lo;
}

extern "C" void kernel_launch(void* const* d_in, const int* in_sizes, int n_in,
                              void* d_out, int out_size, void* d_ws, size_t ws_size,
                              hipStream_t stream) {
    const float* x         = (const float*)d_in[0];
    const float* norm_w    = (const float*)d_in[1];
    const float* norm_b    = (const float*)d_in[2];
    const float* in_proj_w = (const float*)d_in[3];
    const float* conv_w    = (const float*)d_in[4];
    const float* conv_b    = (const float*)d_in[5];
    const float* x_proj_w  = (const float*)d_in[6];
    const float* dt_proj_w = (const float*)d_in[7];
    const float* dt_proj_b = (const float*)d_in[8];
    const float* A_log     = (const float*)d_in[9];
    const float* Dvec      = (const float*)d_in[10];
    const float* out_proj_w= (const float*)d_in[11];
    float* out = (float*)d_out;
    float* ws  = (float*)d_ws;

    const size_t M1 = (size_t)1024 * 1024;
    float* dtT    = ws;                 // 4M f
    float* xi_duT = ws + 4*M1;          // xiraw (dead after conv_pack) -> duT
    float* zbuf   = ws + 8*M1;
    float* xibuf  = ws + 12*M1;
    float* xdbl   = ws + 16*M1;         // 0.64M f (atomic-accumulated)
    unsigned short* ytbuf = (unsigned short*)(ws + 17*M1);  // 2M u16 (bf16 y)
    unsigned short* Apack = (unsigned short*)(ws + 21*M1);  // 20MB region
    unsigned int*   bcbuf = (unsigned int*)(ws + 21*M1);    // overlaps Apack (ordered)
    unsigned short* BpIn  = (unsigned short*)(ws + 26*M1);
    unsigned short* BpX   = (unsigned short*)(ws + 27*M1);
    unsigned short* BpOut = (unsigned short*)(ws + 27*M1 + 512*1024);

    // ---- prologue: LN+A-pack | BpIn pack | xdbl zero (928 blocks) ----
    prologue<<<928, 256, 0, stream>>>(x, norm_w, norm_b, in_proj_w,
        Apack, BpIn, xdbl);

    // ---- in_proj: M=4096,N=2048,K=512; 1-term; 64x128 tile -> 1024 blocks ----
    gemm_mfma<64,128,2,2,false><<<dim3(16, 64), 256, 0, stream>>>(
        Apack, BpIn, 4096, 2048, 512, /*cols3=*/DINNER, /*tk=*/1,
        xi_duT, zbuf, DINNER);

    // ---- fused conv+SiLU+pack (+BpX pack in tail blocks) ----
    conv_pack<<<2048 + 128, 256, 0, stream>>>(
        xi_duT, conv_w, conv_b, xibuf, Apack, x_proj_w, BpX);

    // ---- x_proj: split-K x4, dt cols 2-term; z=(kchunk<<1)|term, atomics ----
    gemm_mfma<128,64,2,2,true><<<dim3(3, 32, 8), 256, 0, stream>>>(
        Apack, BpX, 4096, 256, 1024, /*cols3=*/64, /*tk=ksplit*/4,
        xdbl, nullptr, XDBL_W);

    // ---- dt/du transposes + quad-bc pack (one kernel); then scan ----
    dtdu_kernel<<<1024 + 64, 256, 0, stream>>>(xdbl, dt_proj_w, dt_proj_b,
        xibuf, dtT, xi_duT, bcbuf);
    scan_kernel<<<(BSZ * DINNER) / 4, 256, 0, stream>>>(
        dtT, xi_duT, bcbuf, A_log, ytbuf);

    // ---- fused gate+pack (+BpOut pack in tail blocks) ----
    gate_pack<<<2048 + 256, 256, 0, stream>>>(
        ytbuf, xibuf, zbuf, Dvec, Apack, out_proj_w, BpOut);

    // ---- out_proj: M=4096,N=512,K=1024; 1-term bf16 ----
    gemm_mfma<64,64,2,2,false><<<dim3(8, 64), 256, 0, stream>>>(
        Apack, BpOut, 4096, 512, 1024, /*cols3=*/512, /*tk=*/1,
        out, nullptr, D_MODEL);
}